// Round 2
// baseline (388.272 us; speedup 1.0000x reference)
//
#include <hip/hip_runtime.h>

typedef _Float16 f16;
typedef f16 f16x8 __attribute__((ext_vector_type(8)));
typedef f16 f16x4 __attribute__((ext_vector_type(4)));
typedef float f32x4 __attribute__((ext_vector_type(4)));

#define NB 4
#define NS 2048
#define ND 1024
#define NH 16
#define NDH 64

__device__ __forceinline__ void gl2lds16(const void* g, void* l) {
  __builtin_amdgcn_global_load_lds(
      (const __attribute__((address_space(1))) unsigned int*)g,
      (__attribute__((address_space(3))) unsigned int*)l, 16, 0, 0);
}

__device__ __forceinline__ float fast_exp2(float x) {
  return __builtin_amdgcn_exp2f(x);  // v_exp_f32
}

// ---------------- fp32 -> f16 conversion ----------------
__global__ __launch_bounds__(256) void cvt_kernel(const float* __restrict__ src,
                                                  f16* __restrict__ dst, int n4) {
  int i = blockIdx.x * 256 + threadIdx.x;
  if (i >= n4) return;
  float4 v = ((const float4*)src)[i];
  f16x4 h = {(f16)v.x, (f16)v.y, (f16)v.z, (f16)v.w};
  ((f16x4*)dst)[i] = h;
}

// ---------------- fused QKV projection GEMM ----------------
// C[m][n] = sum_k X[m][k] * W[n][k] + bias[n], m in [0,8192), n in [0,3072)
// Output scattered to QKV[mat][b][h][s][dh] as f16.
__global__ __launch_bounds__(256) void qkv_gemm(
    const f16* __restrict__ Xh, const f16* __restrict__ Wh,
    const float* __restrict__ bq, const float* __restrict__ bk,
    const float* __restrict__ bv, f16* __restrict__ QKV) {
  __shared__ f16 Ah[128 * 32];
  __shared__ f16 Bh[128 * 32];
  const int t = threadIdx.x;
  const int tileM = blockIdx.x * 128;
  const int nGlob = blockIdx.y * 128;
  const int mat = nGlob >> 10;
  const int col0 = nGlob & 1023;
  const int wave = t >> 6, lane = t & 63;
  const int mOff = (wave & 1) * 64, nOff = (wave >> 1) * 64;
  const int lr = lane & 15, quad = lane >> 4;

  f32x4 acc[4][4];
#pragma unroll
  for (int i = 0; i < 4; i++)
#pragma unroll
    for (int j = 0; j < 4; j++) acc[i][j] = f32x4{0.f, 0.f, 0.f, 0.f};

  const int srow = t >> 2, schunk = (t & 3) * 8;
  const f16* ag = Xh + (size_t)(tileM + srow) * ND + schunk;
  const f16* bg = Wh + (size_t)mat * ND * ND + (size_t)(col0 + srow) * ND + schunk;

  for (int kk = 0; kk < ND; kk += 32) {
    __syncthreads();
    gl2lds16(ag + kk, Ah + t * 8);
    gl2lds16(ag + (size_t)64 * ND + kk, Ah + 2048 + t * 8);
    gl2lds16(bg + kk, Bh + t * 8);
    gl2lds16(bg + (size_t)64 * ND + kk, Bh + 2048 + t * 8);
    __syncthreads();
    f16x8 af[4], bf[4];
#pragma unroll
    for (int i = 0; i < 4; i++)
      af[i] = *(const f16x8*)(Ah + (mOff + i * 16 + lr) * 32 + quad * 8);
#pragma unroll
    for (int j = 0; j < 4; j++)
      bf[j] = *(const f16x8*)(Bh + (nOff + j * 16 + lr) * 32 + quad * 8);
#pragma unroll
    for (int i = 0; i < 4; i++)
#pragma unroll
      for (int j = 0; j < 4; j++)
        acc[i][j] = __builtin_amdgcn_mfma_f32_16x16x32_f16(af[i], bf[j], acc[i][j], 0, 0, 0);
  }

  const float* bias = (mat == 0) ? bq : (mat == 1) ? bk : bv;
#pragma unroll
  for (int j = 0; j < 4; j++) {
    int n = col0 + nOff + j * 16 + lr;
    float bb = bias[n];
    int h = n >> 6, dh = n & 63;
#pragma unroll
    for (int i = 0; i < 4; i++) {
      int mbase = tileM + mOff + i * 16 + quad * 4;
#pragma unroll
      for (int r = 0; r < 4; r++) {
        int m = mbase + r;
        int b = m >> 11, s = m & 2047;
        size_t idx = ((((size_t)mat * NB + b) * NH + h) * NS + s) * NDH + dh;
        QKV[idx] = (f16)(acc[i][j][r] + bb);
      }
    }
  }
}

// ---------------- flash attention ----------------
// grid: (16 q-blocks, 64 b*h). block: 256 threads = 4 waves, each wave owns 32 q rows.
__global__ __launch_bounds__(256) void attn_kernel(const f16* __restrict__ QKV,
                                                   float* __restrict__ out) {
  __shared__ f16 Vt[64][136];    // V transposed: [dh][key], pad->2-way (free) banks
  __shared__ f16 Pl[128][136];   // P round-trip (C/D layout -> A layout), within-wave rows
  const int t = threadIdx.x, wave = t >> 6, lane = t & 63;
  const int lr = lane & 15, quad = lane >> 4;
  const int qb = blockIdx.x, bh = blockIdx.y;
  const int bb = bh >> 4, hh = bh & 15;
  const f16* Q = QKV + (size_t)bh * (NS * NDH);
  const f16* K = QKV + (size_t)(64 + bh) * (NS * NDH);
  const f16* V = QKV + (size_t)(128 + bh) * (NS * NDH);
  const int q0 = qb * 128 + wave * 32;

  // Q fragments: register-resident for whole kernel. A-layout: m=lane&15, k=quad*8+j
  f16x8 qf[2][2];
#pragma unroll
  for (int i = 0; i < 2; i++)
#pragma unroll
    for (int ks = 0; ks < 2; ks++)
      qf[i][ks] = *(const f16x8*)(Q + (size_t)(q0 + i * 16 + lr) * NDH + ks * 32 + quad * 8);

  f32x4 o[2][4];
  float mrow[2][4], lsum[2][4];
#pragma unroll
  for (int i = 0; i < 2; i++)
#pragma unroll
    for (int r = 0; r < 4; r++) {
      mrow[i][r] = -1e30f;
      lsum[i][r] = 0.f;
    }
#pragma unroll
  for (int i = 0; i < 2; i++)
#pragma unroll
    for (int j = 0; j < 4; j++) o[i][j] = f32x4{0.f, 0.f, 0.f, 0.f};

  for (int kt = 0; kt < 16; kt++) {
    const int k0 = kt * 128;
    __syncthreads();  // prev PV reads of Vt complete before restage
    // stage V transposed into LDS (row = c&127 keeps ds_write banks conflict-free)
#pragma unroll
    for (int ci = 0; ci < 4; ci++) {
      int c = ci * 256 + t;
      int row = c & 127, cb = c >> 7;
      f16x8 v = *(const f16x8*)(V + (size_t)(k0 + row) * NDH + cb * 8);
#pragma unroll
      for (int j = 0; j < 8; j++) Vt[cb * 8 + j][row] = v[j];
    }
    // S = Q K^T : K B-frags straight from global (L1-resident, 16B contiguous)
    f32x4 s[2][8];
#pragma unroll
    for (int i = 0; i < 2; i++)
#pragma unroll
      for (int j = 0; j < 8; j++) s[i][j] = f32x4{0.f, 0.f, 0.f, 0.f};
#pragma unroll
    for (int j = 0; j < 8; j++) {
#pragma unroll
      for (int ks = 0; ks < 2; ks++) {
        f16x8 kf = *(const f16x8*)(K + (size_t)(k0 + j * 16 + lr) * NDH + ks * 32 + quad * 8);
        s[0][j] = __builtin_amdgcn_mfma_f32_16x16x32_f16(qf[0][ks], kf, s[0][j], 0, 0, 0);
        s[1][j] = __builtin_amdgcn_mfma_f32_16x16x32_f16(qf[1][ks], kf, s[1][j], 0, 0, 0);
      }
    }
    // online softmax, scaled-log2 domain: p = exp2(s*Cs - m)
    const float Cs = 0.125f * 1.44269504f;
#pragma unroll
    for (int i = 0; i < 2; i++)
#pragma unroll
      for (int r = 0; r < 4; r++) {
        float mx = s[i][0][r];
#pragma unroll
        for (int j = 1; j < 8; j++) mx = fmaxf(mx, s[i][j][r]);
        mx = fmaxf(mx, __shfl_xor(mx, 1));
        mx = fmaxf(mx, __shfl_xor(mx, 2));
        mx = fmaxf(mx, __shfl_xor(mx, 4));
        mx = fmaxf(mx, __shfl_xor(mx, 8));
        mx *= Cs;
        float mn = fmaxf(mrow[i][r], mx);
        float alpha = fast_exp2(mrow[i][r] - mn);
        mrow[i][r] = mn;
        float sum = 0.f;
        int prow = wave * 32 + i * 16 + quad * 4 + r;
#pragma unroll
        for (int j = 0; j < 8; j++) {
          float p = fast_exp2(__builtin_fmaf(s[i][j][r], Cs, -mn));
          sum += p;
          Pl[prow][j * 16 + lr] = (f16)p;
        }
        sum += __shfl_xor(sum, 1);
        sum += __shfl_xor(sum, 2);
        sum += __shfl_xor(sum, 4);
        sum += __shfl_xor(sum, 8);
        lsum[i][r] = lsum[i][r] * alpha + sum;
#pragma unroll
        for (int j = 0; j < 4; j++) o[i][j][r] *= alpha;
      }
    __syncthreads();  // Vt staged; P is within-wave (lgkmcnt handles it)
    // O += P V  (A = P from LDS, B = Vt rows = V^T)
#pragma unroll
    for (int ks = 0; ks < 4; ks++) {
      f16x8 pf[2];
      pf[0] = *(const f16x8*)(&Pl[wave * 32 + lr][ks * 32 + quad * 8]);
      pf[1] = *(const f16x8*)(&Pl[wave * 32 + 16 + lr][ks * 32 + quad * 8]);
#pragma unroll
      for (int j = 0; j < 4; j++) {
        f16x8 vf = *(const f16x8*)(&Vt[j * 16 + lr][ks * 32 + quad * 8]);
        o[0][j] = __builtin_amdgcn_mfma_f32_16x16x32_f16(pf[0], vf, o[0][j], 0, 0, 0);
        o[1][j] = __builtin_amdgcn_mfma_f32_16x16x32_f16(pf[1], vf, o[1][j], 0, 0, 0);
      }
    }
  }
  // epilogue: O /= l, write fp32 [B,S,D]
#pragma unroll
  for (int i = 0; i < 2; i++)
#pragma unroll
    for (int r = 0; r < 4; r++) {
      float inv = 1.0f / lsum[i][r];
      int q = q0 + i * 16 + quad * 4 + r;
#pragma unroll
      for (int j = 0; j < 4; j++)
        out[((size_t)bb * NS + q) * ND + hh * NDH + j * 16 + lr] = o[i][j][r] * inv;
    }
}

extern "C" void kernel_launch(void* const* d_in, const int* in_sizes, int n_in,
                              void* d_out, int out_size, void* d_ws, size_t ws_size,
                              hipStream_t stream) {
  const float* X  = (const float*)d_in[0];
  const float* Wq = (const float*)d_in[1];
  const float* bq = (const float*)d_in[2];
  const float* Wk = (const float*)d_in[3];
  const float* bk = (const float*)d_in[4];
  const float* Wv = (const float*)d_in[5];
  const float* bv = (const float*)d_in[6];
  float* out = (float*)d_out;

  // ws layout: Xh 16MB | Wh 6MB | QKV f16 48MB  (total 70MB)
  f16* Xh  = (f16*)d_ws;
  f16* Wh  = (f16*)((char*)d_ws + (size_t)(16u << 20));
  f16* QKV = (f16*)((char*)d_ws + (size_t)(22u << 20));

  cvt_kernel<<<8192, 256, 0, stream>>>(X, Xh, 2097152);
  cvt_kernel<<<1024, 256, 0, stream>>>(Wq, Wh, 262144);
  cvt_kernel<<<1024, 256, 0, stream>>>(Wk, Wh + (1u << 20), 262144);
  cvt_kernel<<<1024, 256, 0, stream>>>(Wv, Wh + (2u << 20), 262144);
  qkv_gemm<<<dim3(64, 24), 256, 0, stream>>>(Xh, Wh, bq, bk, bv, QKV);
  attn_kernel<<<dim3(16, 64), 256, 0, stream>>>(QKV, out);
}